// Round 3
// baseline (483.723 us; speedup 1.0000x reference)
//
#include <hip/hip_runtime.h>
#include <hip/hip_bf16.h>
#include <math.h>

// FEAf lowpass: b=4, t=2048, c=64, mw=64, modes=16, SCALE=1/4096.
// Stage A: 16-mode DFT over t (radix-2 fold t vs t+1024), float4 lanes.
// reduceP: sum 16 chunk partials.
// Stage B: per (b,h) complex 16x16 attention w/ complex tanh.
// Stage C: 16-mode inverse (radix-2 Hermitian fold), float4 lanes.

#define T_DIM 2048
#define DH 4096           // c*mw
#define DH4 1024          // float4 view
#define CH 16             // stageA chunks over t-pair index [0,1024)
#define TPCH 64           // t-pairs per chunk
#define CTT 16            // stageC t-pairs per block

// ---------------- twiddle tables ----------------
// WA[t'][2m]=cos(2pi m t'/2048), [2m+1]=sin(...)               t' in [0,1024)
// Bt2[t][2m]=coef_m cos(2pi m t/2048), [2m+1]=-coef_m sin(...) t in [0,1024)
//   coef_m=(m==0?1:2)*SCALE/2048; sin entry for m==0 is 0.
__global__ void init_tables(float* __restrict__ WA, float* __restrict__ Bt2) {
    int i = blockIdx.x * 256 + threadIdx.x;
    const float TWO_PI = 6.2831853071795864769f;
    if (i < 1024 * 32) {
        int t = i >> 5, r = i & 31, m = r >> 1;
        int ph = (m * t) & 2047;
        float ang = TWO_PI * (float)ph * (1.0f / 2048.0f);
        WA[i] = (r & 1) ? sinf(ang) : cosf(ang);
    }
    int i2 = i - 1024 * 32;
    if (i2 >= 0 && i2 < 1024 * 32) {
        int t = i2 >> 5, r = i2 & 31, m = r >> 1;
        int ph = (m * t) & 2047;
        float ang = TWO_PI * (float)ph * (1.0f / 2048.0f);
        const float S2 = 1.0f / (4096.0f * 2048.0f);
        float coef = (m == 0 ? 1.0f : 2.0f) * S2;
        float val;
        if (!(r & 1)) val = coef * cosf(ang);
        else          val = (m == 0) ? 0.0f : -coef * sinf(ang);
        Bt2[i2] = val;
    }
}

// ---------------- stage A ----------------
// P[tz][chunk][j][dh]; j: 0..15 Re, 16..31 Im (Im = -sum x sin). tz=tensor*4+b.
__global__ __launch_bounds__(256) void stageA(
        const float* __restrict__ q, const float* __restrict__ k,
        const float* __restrict__ v, const float4* __restrict__ WA4,
        float4* __restrict__ P4) {
    __shared__ float4 w4[TPCH * 8];   // 8 KB twiddle tile
    int tid = threadIdx.x;
    int c   = blockIdx.y;
    int tz  = blockIdx.z;
    int tensor = tz >> 2, b = tz & 3;

    w4[tid]       = WA4[c * (TPCH * 8) + tid];
    w4[tid + 256] = WA4[c * (TPCH * 8) + tid + 256];
    __syncthreads();

    int dh4 = blockIdx.x * 256 + tid;    // float4 index into DH
    const float* srcf = (tensor == 0 ? q : tensor == 1 ? k : v)
                        + (size_t)b * T_DIM * DH;
    const float4* p0 = (const float4*)srcf + (size_t)(c * TPCH) * DH4 + dh4;

    float4 aR[16], aI[16];
    #pragma unroll
    for (int m = 0; m < 16; m++) {
        aR[m] = make_float4(0.f, 0.f, 0.f, 0.f);
        aI[m] = make_float4(0.f, 0.f, 0.f, 0.f);
    }

    #pragma unroll 2
    for (int tl = 0; tl < TPCH; tl++) {
        float4 a = p0[(size_t)tl * DH4];
        float4 bb = p0[(size_t)(tl + 1024) * DH4];
        float4 u = make_float4(a.x + bb.x, a.y + bb.y, a.z + bb.z, a.w + bb.w);
        float4 d = make_float4(a.x - bb.x, a.y - bb.y, a.z - bb.z, a.w - bb.w);
        const float4* ww = &w4[tl * 8];
        #pragma unroll
        for (int kk = 0; kk < 8; kk++) {
            float4 t4 = ww[kk];   // {cos(2k), sin(2k), cos(2k+1), sin(2k+1)}
            int me = 2 * kk, mo = 2 * kk + 1;
            aR[me].x = fmaf(t4.x, u.x, aR[me].x);
            aR[me].y = fmaf(t4.x, u.y, aR[me].y);
            aR[me].z = fmaf(t4.x, u.z, aR[me].z);
            aR[me].w = fmaf(t4.x, u.w, aR[me].w);
            aI[me].x = fmaf(-t4.y, u.x, aI[me].x);
            aI[me].y = fmaf(-t4.y, u.y, aI[me].y);
            aI[me].z = fmaf(-t4.y, u.z, aI[me].z);
            aI[me].w = fmaf(-t4.y, u.w, aI[me].w);
            aR[mo].x = fmaf(t4.z, d.x, aR[mo].x);
            aR[mo].y = fmaf(t4.z, d.y, aR[mo].y);
            aR[mo].z = fmaf(t4.z, d.z, aR[mo].z);
            aR[mo].w = fmaf(t4.z, d.w, aR[mo].w);
            aI[mo].x = fmaf(-t4.w, d.x, aI[mo].x);
            aI[mo].y = fmaf(-t4.w, d.y, aI[mo].y);
            aI[mo].z = fmaf(-t4.w, d.z, aI[mo].z);
            aI[mo].w = fmaf(-t4.w, d.w, aI[mo].w);
        }
    }
    float4* pp = P4 + (((size_t)tz * CH + c) * 32) * DH4 + dh4;
    #pragma unroll
    for (int m = 0; m < 16; m++) {
        pp[(size_t)m * DH4]        = aR[m];
        pp[(size_t)(16 + m) * DH4] = aI[m];
    }
}

// ---------------- reduce chunk partials: Y[tz][j][dh] ----------------
__global__ __launch_bounds__(256) void reduceP(const float4* __restrict__ P,
                                               float4* __restrict__ Y) {
    size_t i   = (size_t)blockIdx.x * 256 + threadIdx.x;  // 12*32*1024
    size_t dh4 = i & 1023;
    size_t j   = (i >> 10) & 31;
    size_t tz  = i >> 15;
    const float4* p = P + ((tz * CH) * 32 + j) * DH4 + dh4;
    float4 s = make_float4(0.f, 0.f, 0.f, 0.f);
    #pragma unroll
    for (int cc = 0; cc < CH; cc++) {
        float4 t = p[(size_t)cc * 32 * DH4];
        s.x += t.x; s.y += t.y; s.z += t.z; s.w += t.w;
    }
    Y[i] = s;
}

// ---------------- stage B: complex mode-space attention ----------------
// G[b][j][dh], j: 0..15 Re(qkv), 16..31 Im(qkv)
__global__ __launch_bounds__(256) void stageB(const float* __restrict__ Y,
                                              float* __restrict__ G) {
    __shared__ float qf[64 * 33];
    __shared__ float kf[64 * 33];
    __shared__ float vf[64 * 33];
    __shared__ float qkr[16 * 17];
    __shared__ float qki[16 * 17];

    int tid = threadIdx.x;
    int bh  = blockIdx.x;
    int b   = bh >> 6;
    int h   = bh & 63;

    #pragma unroll
    for (int tensor = 0; tensor < 3; tensor++) {
        float* dst = (tensor == 0 ? qf : tensor == 1 ? kf : vf);
        const float* yp = Y + ((size_t)(tensor * 4 + b) * 32) * DH + h;
        #pragma unroll
        for (int it = 0; it < 8; it++) {
            int p = it * 256 + tid;
            int d = p & 63, j = p >> 6;
            dst[d * 33 + j] = yp[(size_t)j * DH + d * 64];
        }
    }
    __syncthreads();

    int x = tid >> 4, y = tid & 15;
    float ar = 0.f, ai = 0.f;
    #pragma unroll 4
    for (int d = 0; d < 64; d++) {
        float qr = qf[d * 33 + x],      qi = qf[d * 33 + 16 + x];
        float kr = kf[d * 33 + y],      ki = kf[d * 33 + 16 + y];
        ar += qr * kr - qi * ki;
        ai += qr * ki + qi * kr;
    }
    float re, im;
    float a2 = 2.f * ar, b2 = 2.f * ai;
    if (fabsf(a2) < 80.f) {
        float den = coshf(a2) + cosf(b2);
        re = sinhf(a2) / den;
        im = sinf(b2) / den;
    } else {
        re = copysignf(1.f, ar);
        im = 0.f;
    }
    qkr[x * 17 + y] = re;
    qki[x * 17 + y] = im;
    __syncthreads();

    int xx = tid & 15, db = tid >> 4;
    #pragma unroll
    for (int i = 0; i < 4; i++) {
        int d = db + i * 16;
        float cr = 0.f, ci = 0.f;
        #pragma unroll
        for (int yy = 0; yy < 16; yy++) {
            float tr = qkr[xx * 17 + yy], ti = qki[xx * 17 + yy];
            float vr = vf[d * 33 + yy],   vi = vf[d * 33 + 16 + yy];
            cr += tr * vr - ti * vi;
            ci += tr * vi + ti * vr;
        }
        G[((size_t)b * 32 + xx) * DH + d * 64 + h]      = cr;
        G[((size_t)b * 32 + 16 + xx) * DH + d * 64 + h] = ci;
    }
}

// ---------------- stage C: inverse, radix-2 Hermitian fold ----------------
// out[t] = E + O, out[t+1024] = E - O; E/O = even/odd-mode sums.
__global__ __launch_bounds__(256) void stageC(const float4* __restrict__ G4,
                                              const float4* __restrict__ Bt4,
                                              float4* __restrict__ out4) {
    __shared__ float4 w4[CTT * 8];   // 2 KB basis tile
    int tid = threadIdx.x;
    int c   = blockIdx.y;            // t-pair tile, 64 tiles of 16
    int b   = blockIdx.z;

    if (tid < CTT * 8) w4[tid] = Bt4[c * (CTT * 8) + tid];
    __syncthreads();

    int dh4 = blockIdx.x * 256 + tid;
    float4 gr[16], gi[16];
    const float4* gp = G4 + (size_t)b * 32 * DH4 + dh4;
    #pragma unroll
    for (int m = 0; m < 16; m++) {
        gr[m] = gp[(size_t)m * DH4];
        gi[m] = gp[(size_t)(16 + m) * DH4];
    }

    float4* o0 = out4 + ((size_t)b * T_DIM + (size_t)c * CTT) * DH4 + dh4;
    #pragma unroll 2
    for (int tl = 0; tl < CTT; tl++) {
        const float4* ww = &w4[tl * 8];
        float4 E = make_float4(0.f, 0.f, 0.f, 0.f);
        float4 O = make_float4(0.f, 0.f, 0.f, 0.f);
        #pragma unroll
        for (int kk = 0; kk < 8; kk++) {
            float4 t4 = ww[kk];  // {coef*cos(2k), -coef*sin(2k), coef*cos(2k+1), -coef*sin(2k+1)}
            int me = 2 * kk, mo = 2 * kk + 1;
            E.x = fmaf(t4.x, gr[me].x, fmaf(t4.y, gi[me].x, E.x));
            E.y = fmaf(t4.x, gr[me].y, fmaf(t4.y, gi[me].y, E.y));
            E.z = fmaf(t4.x, gr[me].z, fmaf(t4.y, gi[me].z, E.z));
            E.w = fmaf(t4.x, gr[me].w, fmaf(t4.y, gi[me].w, E.w));
            O.x = fmaf(t4.z, gr[mo].x, fmaf(t4.w, gi[mo].x, O.x));
            O.y = fmaf(t4.z, gr[mo].y, fmaf(t4.w, gi[mo].y, O.y));
            O.z = fmaf(t4.z, gr[mo].z, fmaf(t4.w, gi[mo].z, O.z));
            O.w = fmaf(t4.z, gr[mo].w, fmaf(t4.w, gi[mo].w, O.w));
        }
        o0[(size_t)tl * DH4] =
            make_float4(E.x + O.x, E.y + O.y, E.z + O.z, E.w + O.w);
        o0[(size_t)(tl + 1024) * DH4] =
            make_float4(E.x - O.x, E.y - O.y, E.z - O.z, E.w - O.w);
    }
}

extern "C" void kernel_launch(void* const* d_in, const int* in_sizes, int n_in,
                              void* d_out, int out_size, void* d_ws, size_t ws_size,
                              hipStream_t stream) {
    const float* q = (const float*)d_in[0];
    const float* k = (const float*)d_in[1];
    const float* v = (const float*)d_in[2];
    float* out = (float*)d_out;

    char* ws = (char*)d_ws;
    float* WA  = (float*)ws;                          //    131072 B
    float* Bt2 = (float*)(ws + 131072);               //    131072 B
    float* P   = (float*)(ws + 262144);               // 100663296 B
    float* Y   = (float*)(ws + 262144 + 100663296);   //   6291456 B
    float* G   = (float*)(ws + 262144 + 100663296 + 6291456);  // 2 MB

    init_tables<<<256, 256, 0, stream>>>(WA, Bt2);
    stageA<<<dim3(4, CH, 12), 256, 0, stream>>>(q, k, v, (const float4*)WA,
                                                (float4*)P);
    reduceP<<<1536, 256, 0, stream>>>((const float4*)P, (float4*)Y);
    stageB<<<256, 256, 0, stream>>>(Y, G);
    stageC<<<dim3(4, 64, 4), 256, 0, stream>>>((const float4*)G,
                                               (const float4*)Bt2,
                                               (float4*)out);
}